// Round 5
// baseline (109.375 us; speedup 1.0000x reference)
//
#include <hip/hip_runtime.h>
#include <hip/hip_bf16.h>

typedef __attribute__((ext_vector_type(8))) short bf16x8;
typedef __attribute__((ext_vector_type(4))) float f32x4;

#define S_  2048
#define D_  1024
#define H_  16
#define QK_SCALE 0.18033688011f  /* (1/8) * log2(e), folded into W_q */

__device__ __forceinline__ unsigned short f2bf(float x) {
    union { float f; unsigned u; } v; v.f = x;
    unsigned r = v.u + 0x7fffu + ((v.u >> 16) & 1u);
    return (unsigned short)(r >> 16);
}

__device__ __forceinline__ unsigned short bfbits(float x) {
    union { __hip_bfloat16 h; unsigned short s; } c;
    c.h = __float2bfloat16(x);
    return c.s;
}

__device__ __forceinline__ void gload16(const unsigned short* g, unsigned short* l) {
    __builtin_amdgcn_global_load_lds((const __attribute__((address_space(1))) void*)g,
                                     (__attribute__((address_space(3))) void*)l, 16, 0, 0);
}

__device__ __forceinline__ void drain_vm() {
    asm volatile("s_waitcnt vmcnt(0)" ::: "memory");
}

// ---------------- convert f32 -> bf16, 3 tensors fused ----------------
__global__ __launch_bounds__(256) void cvt_f32_bf16(const float* __restrict__ i0,
                                                    const float* __restrict__ i1,
                                                    const float* __restrict__ i2,
                                                    unsigned short* __restrict__ o0,
                                                    unsigned short* __restrict__ o1,
                                                    unsigned short* __restrict__ o2, int n4) {
    int i = blockIdx.x * 256 + threadIdx.x;
    if (i >= n4) return;
    const float* in = blockIdx.y == 0 ? i0 : blockIdx.y == 1 ? i1 : i2;
    unsigned short* out = blockIdx.y == 0 ? o0 : blockIdx.y == 1 ? o1 : o2;
    float4 v = ((const float4*)in)[i];
    ushort4 o;
    o.x = f2bf(v.x); o.y = f2bf(v.y); o.z = f2bf(v.z); o.w = f2bf(v.w);
    ((ushort4*)out)[i] = o;
}

// ---------------- per-head weight transpose f32 -> bf16 (Q gets QK_SCALE) ----------------
__global__ void transpose_qkv(const float* __restrict__ Wq, const float* __restrict__ Wk,
                              const float* __restrict__ Wv, unsigned short* __restrict__ Oq,
                              unsigned short* __restrict__ Ok, unsigned short* __restrict__ Ov) {
    __shared__ float t[32][33];
    int which = blockIdx.z >> 4, h = blockIdx.z & 15;
    const float* I = (which == 0 ? Wq : which == 1 ? Wk : Wv) + (long)h * 65536;
    unsigned short* O = (which == 0 ? Oq : which == 1 ? Ok : Ov) + (long)h * 65536;
    float sc = which == 0 ? QK_SCALE : 1.0f;
    int c0 = blockIdx.x * 32, r0 = blockIdx.y * 32;
    t[threadIdx.y][threadIdx.x] = I[(long)(r0 + threadIdx.y) * 64 + c0 + threadIdx.x];
    __syncthreads();
    O[(long)(c0 + threadIdx.y) * 1024 + r0 + threadIdx.x] = f2bf(sc * t[threadIdx.x][threadIdx.y]);
}

__global__ void transpose_wo(const float* __restrict__ in, unsigned short* __restrict__ out) {
    __shared__ float t[32][33];
    int c0 = blockIdx.x * 32, r0 = blockIdx.y * 32;
    t[threadIdx.y][threadIdx.x] = in[(long)(r0 + threadIdx.y) * 1024 + c0 + threadIdx.x];
    __syncthreads();
    out[(long)(c0 + threadIdx.y) * 1024 + r0 + threadIdx.x] = f2bf(t[threadIdx.x][threadIdx.y]);
}

// ---------------- 128x128-tile bf16 MFMA GEMM, 2x2 waves, double-buffered ----------------
// C[m][n] = sum_k A[m][k]*Bt[n][k]; A [M][1024], Bt [N][1024] bf16.
// MODE 0: bf16 C[gm*ldc+gn]; MODE 1: bf16 KEY-PERMUTED transposed store; MODE 2: f32
template<int MODE>
__device__ __forceinline__ void gemm128x128(unsigned short (*As)[128 * 64],
                                            unsigned short (*Bs)[128 * 64],
                                            const unsigned short* __restrict__ A,
                                            const unsigned short* __restrict__ Bt,
                                            void* __restrict__ C, int m0, int n0, int ldc) {
    const int tid = threadIdx.x, wv = tid >> 6, lane = tid & 63, lg = lane >> 4, lr = lane & 15;
    const int wm = wv & 1, wn = wv >> 1;
    f32x4 acc[4][4] = {};
    const unsigned short* Ab = A + (size_t)m0 * D_;
    const unsigned short* Bb = Bt + (size_t)n0 * D_;
    auto stage = [&](int b, int kt) {
        #pragma unroll
        for (int it = 0; it < 4; ++it) {
            int c = it * 256 + wv * 64 + lane;
            int row = c >> 3, jj = (c & 7) ^ (row & 7);
            gload16(Ab + (size_t)row * D_ + kt * 64 + jj * 8, &As[b][(it * 256 + wv * 64) * 8]);
        }
        #pragma unroll
        for (int it = 0; it < 4; ++it) {
            int c = it * 256 + wv * 64 + lane;
            int row = c >> 3, jj = (c & 7) ^ (row & 7);
            gload16(Bb + (size_t)row * D_ + kt * 64 + jj * 8, &Bs[b][(it * 256 + wv * 64) * 8]);
        }
    };
    stage(0, 0);
    drain_vm();
    __syncthreads();
    int buf = 0;
    for (int kt = 0; kt < 16; ++kt) {
        if (kt + 1 < 16) stage(buf ^ 1, kt + 1);
        #pragma unroll
        for (int kk = 0; kk < 2; ++kk) {
            bf16x8 af[4], bfr[4];
            #pragma unroll
            for (int mf = 0; mf < 4; ++mf) {
                int r = wm * 64 + mf * 16 + lr;
                af[mf] = *(const bf16x8*)&As[buf][(r * 8 + ((kk * 4 + lg) ^ (r & 7))) * 8];
            }
            #pragma unroll
            for (int nf = 0; nf < 4; ++nf) {
                int r = wn * 64 + nf * 16 + lr;
                bfr[nf] = *(const bf16x8*)&Bs[buf][(r * 8 + ((kk * 4 + lg) ^ (r & 7))) * 8];
            }
            #pragma unroll
            for (int mf = 0; mf < 4; ++mf)
                #pragma unroll
                for (int nf = 0; nf < 4; ++nf)
                    acc[mf][nf] = __builtin_amdgcn_mfma_f32_16x16x32_bf16(af[mf], bfr[nf], acc[mf][nf], 0, 0, 0);
        }
        drain_vm();
        __syncthreads();
        buf ^= 1;
    }
    #pragma unroll
    for (int mf = 0; mf < 4; ++mf)
        #pragma unroll
        for (int nf = 0; nf < 4; ++nf) {
            if (MODE == 1) {
                // key-permuted transposed store (verified mapping): within each 32-key
                // group, key 16b+4lg+j stored at position 8lg+4b+j (b = mf&1)
                int gn = n0 + wn * 64 + nf * 16 + lr;
                int pg = m0 + wm * 64 + (mf >> 1) * 32 + lg * 8 + (mf & 1) * 4;
                ushort4 pk;
                pk.x = f2bf(acc[mf][nf][0]); pk.y = f2bf(acc[mf][nf][1]);
                pk.z = f2bf(acc[mf][nf][2]); pk.w = f2bf(acc[mf][nf][3]);
                *(ushort4*)&((unsigned short*)C)[(size_t)gn * ldc + pg] = pk;
            } else {
                #pragma unroll
                for (int j = 0; j < 4; ++j) {
                    int gm = m0 + wm * 64 + mf * 16 + lg * 4 + j;
                    int gn = n0 + wn * 64 + nf * 16 + lr;
                    if (MODE == 0) ((unsigned short*)C)[(size_t)gm * ldc + gn] = f2bf(acc[mf][nf][j]);
                    else           ((float*)C)[(size_t)gm * ldc + gn] = acc[mf][nf][j];
                }
            }
        }
}

__global__ __launch_bounds__(256, 2) void proj_kernel(
    const unsigned short* __restrict__ Eq, const unsigned short* __restrict__ Ek,
    const unsigned short* __restrict__ Ev, const unsigned short* __restrict__ Wqt,
    const unsigned short* __restrict__ Wkt, const unsigned short* __restrict__ Wvt,
    unsigned short* __restrict__ Qb, unsigned short* __restrict__ Kb,
    unsigned short* __restrict__ Vtb) {
    __shared__ alignas(16) unsigned short As[2][128 * 64];
    __shared__ alignas(16) unsigned short Bs[2][128 * 64];
    int m0 = blockIdx.x * 128, n0 = blockIdx.y * 128;
    if (blockIdx.z == 0)      gemm128x128<0>(As, Bs, Eq, Wqt, Qb, m0, n0, 1024);
    else if (blockIdx.z == 1) gemm128x128<0>(As, Bs, Ek, Wkt, Kb, m0, n0, 1024);
    else                      gemm128x128<1>(As, Bs, Ev, Wvt, Vtb, m0, n0, S_);
}

__global__ __launch_bounds__(256, 2) void out_gemm(const unsigned short* __restrict__ Cat,
                                                   const unsigned short* __restrict__ Wot,
                                                   float* __restrict__ Out) {
    __shared__ alignas(16) unsigned short As[2][128 * 64];
    __shared__ alignas(16) unsigned short Bs[2][128 * 64];
    gemm128x128<2>(As, Bs, Cat, Wot, Out, blockIdx.x * 128, blockIdx.y * 128, 1024);
}

// ---------------- flash attention: 32 q/wave, split-KV x2, defer-max ----------------
// grid (S/128, H, 2), 256 thr (4 waves); wave owns q rows [s0+wv*32, +32) as two
// 16-row sets A/B sharing every K/V fragment read. Lane's q within set = lr.
__global__ __launch_bounds__(256, 2) void attn_kernel(
    const unsigned short* __restrict__ Qb, const unsigned short* __restrict__ Kb,
    const unsigned short* __restrict__ Vtb, float* __restrict__ Op, float* __restrict__ Ml) {
    __shared__ alignas(16) unsigned short Ks[2][64 * 64];
    __shared__ alignas(16) unsigned short Vs[2][64 * 64];

    const int h = blockIdx.y, s0 = blockIdx.x * 128, half = blockIdx.z;
    const int tid = threadIdx.x, wv = tid >> 6, lane = tid & 63, lg = lane >> 4, lr = lane & 15;

    const unsigned short* qrA = Qb + (size_t)(s0 + wv * 32 + lr) * D_ + h * 64;
    const unsigned short* qrB = qrA + 16 * D_;
    const bf16x8 qA0 = *(const bf16x8*)(qrA + lg * 8);
    const bf16x8 qA1 = *(const bf16x8*)(qrA + 32 + lg * 8);
    const bf16x8 qB0 = *(const bf16x8*)(qrB + lg * 8);
    const bf16x8 qB1 = *(const bf16x8*)(qrB + 32 + lg * 8);

    // m: lg-uniform running max (floor 0, exact). l: PER-LANE partial sum
    // (this lane's 16 keys/tile); cross-lane reduced once after the loop.
    float mA = 0.f, mB = 0.f, lA = 0.f, lB = 0.f;
    f32x4 oA[4] = {}, oB[4] = {};

    const unsigned short* KhB = Kb + h * 64;
    const unsigned short* VhB = Vtb + (size_t)(h * 64) * S_;  // key-permuted [64 dv][S]

    auto stage = [&](int b, int t) {
        #pragma unroll
        for (int it = 0; it < 2; ++it) {
            int c = it * 256 + wv * 64 + lane;
            int row = c >> 3, jj = (c & 7) ^ (row & 7);
            gload16(KhB + (size_t)(t * 64 + row) * D_ + jj * 8, &Ks[b][(it * 256 + wv * 64) * 8]);
        }
        #pragma unroll
        for (int it = 0; it < 2; ++it) {
            int c = it * 256 + wv * 64 + lane;
            int row = c >> 3, jj = (c & 7) ^ (row & 7);
            gload16(VhB + (size_t)row * S_ + t * 64 + jj * 8, &Vs[b][(it * 256 + wv * 64) * 8]);
        }
    };

    const int t0 = half * 16;
    stage(0, t0);
    drain_vm();
    __syncthreads();
    int buf = 0;
    for (int tt = 0; tt < 16; ++tt) {
        if (tt + 1 < 16) stage(buf ^ 1, t0 + tt + 1);
        const unsigned short* K_ = Ks[buf];
        const unsigned short* V_ = Vs[buf];

        // scores (pre-scaled by QK_SCALE via W_q): key = n*16 + lg*4 + j, q = lr
        f32x4 sa[4] = {}, sb[4] = {};
        __builtin_amdgcn_s_setprio(1);
        #pragma unroll
        for (int kk = 0; kk < 2; ++kk) {
            bf16x8 qa = kk ? qA1 : qA0;
            bf16x8 qb = kk ? qB1 : qB0;
            #pragma unroll
            for (int n = 0; n < 4; ++n) {
                int r = n * 16 + lr;
                bf16x8 kf = *(const bf16x8*)&K_[(r * 8 + ((kk * 4 + lg) ^ (r & 7))) * 8];
                sa[n] = __builtin_amdgcn_mfma_f32_16x16x32_bf16(kf, qa, sa[n], 0, 0, 0);
                sb[n] = __builtin_amdgcn_mfma_f32_16x16x32_bf16(kf, qb, sb[n], 0, 0, 0);
            }
        }
        __builtin_amdgcn_s_setprio(0);

        // defer-max guard: per-lane local max only; rescale is rare
        float mxA = sa[0][0], mxB = sb[0][0];
        #pragma unroll
        for (int n = 0; n < 4; ++n)
            #pragma unroll
            for (int j = 0; j < 4; ++j) {
                mxA = fmaxf(mxA, sa[n][j]);
                mxB = fmaxf(mxB, sb[n][j]);
            }
        if (__any((mxA > mA + 11.f) || (mxB > mB + 11.f))) {
            mxA = fmaxf(mxA, __shfl_xor(mxA, 16)); mxA = fmaxf(mxA, __shfl_xor(mxA, 32));
            mxB = fmaxf(mxB, __shfl_xor(mxB, 16)); mxB = fmaxf(mxB, __shfl_xor(mxB, 32));
            float nA = fmaxf(mA, mxA), nB = fmaxf(mB, mxB);
            float aA = exp2f(mA - nA), aB = exp2f(mB - nB);
            mA = nA; mB = nB; lA *= aA; lB *= aB;
            #pragma unroll
            for (int n = 0; n < 4; ++n) { oA[n] *= aA; oB[n] *= aB; }
        }
        float rsA = 0.f, rsB = 0.f;
        #pragma unroll
        for (int n = 0; n < 4; ++n)
            #pragma unroll
            for (int j = 0; j < 4; ++j) {
                float pa = exp2f(sa[n][j] - mA);
                float pb = exp2f(sb[n][j] - mB);
                sa[n][j] = pa; rsA += pa;
                sb[n][j] = pb; rsB += pb;
            }
        lA += rsA; lB += rsB;

        // pack P to lane-local PV B-frags (hw cvt via __float2bfloat16)
        bf16x8 pA[2], pB[2];
        #pragma unroll
        for (int kk = 0; kk < 2; ++kk) {
            union { bf16x8 v; unsigned short s[8]; } ua, ub;
            #pragma unroll
            for (int i = 0; i < 4; ++i) {
                ua.s[i]     = bfbits(sa[2 * kk][i]);
                ua.s[4 + i] = bfbits(sa[2 * kk + 1][i]);
                ub.s[i]     = bfbits(sb[2 * kk][i]);
                ub.s[4 + i] = bfbits(sb[2 * kk + 1][i]);
            }
            pA[kk] = ua.v; pB[kk] = ub.v;
        }
        // O^T += V^T(perm) * P^T : one 16B read per fragment, shared by both q-sets
        __builtin_amdgcn_s_setprio(1);
        #pragma unroll
        for (int n = 0; n < 4; ++n) {
            int r = n * 16 + lr;
            #pragma unroll
            for (int kk = 0; kk < 2; ++kk) {
                bf16x8 vf = *(const bf16x8*)&V_[(r * 8 + ((kk * 4 + lg) ^ (r & 7))) * 8];
                oA[n] = __builtin_amdgcn_mfma_f32_16x16x32_bf16(vf, pA[kk], oA[n], 0, 0, 0);
                oB[n] = __builtin_amdgcn_mfma_f32_16x16x32_bf16(vf, pB[kk], oB[n], 0, 0, 0);
            }
        }
        __builtin_amdgcn_s_setprio(0);
        drain_vm();
        __syncthreads();
        buf ^= 1;
    }
    // single cross-lane l reduction (over lg groups)
    lA += __shfl_xor(lA, 16); lA += __shfl_xor(lA, 32);
    lB += __shfl_xor(lB, 16); lB += __shfl_xor(lB, 32);

    const int slot = half * 16 + h;
    size_t qa = (size_t)s0 + wv * 32 + lr, qb = qa + 16;
    size_t baseA = ((size_t)slot * S_ + qa) * 64;
    size_t baseB = ((size_t)slot * S_ + qb) * 64;
    #pragma unroll
    for (int n = 0; n < 4; ++n) {
        *(f32x4*)&Op[baseA + n * 16 + lg * 4] = oA[n];
        *(f32x4*)&Op[baseB + n * 16 + lg * 4] = oB[n];
    }
    if (lg == 0) {
        size_t miA = (size_t)slot * S_ + qa, miB = (size_t)slot * S_ + qb;
        Ml[miA * 2] = mA; Ml[miA * 2 + 1] = lA;
        Ml[miB * 2] = mB; Ml[miB * 2 + 1] = lB;
    }
}

// ---------------- combine the 2 KV-halves ----------------
__global__ __launch_bounds__(256) void combine(const float* __restrict__ Op,
                                               const float* __restrict__ Ml,
                                               unsigned short* __restrict__ Cat) {
    int gid = blockIdx.x * 256 + threadIdx.x;          // 16(d4) * 2048(s) * 16(h)
    int d4 = gid & 15, s = (gid >> 4) & 2047, h = gid >> 15;
    size_t i0 = (size_t)h * S_ + s, i1 = (size_t)(16 + h) * S_ + s;
    float m0 = Ml[i0 * 2], l0 = Ml[i0 * 2 + 1];
    float m1 = Ml[i1 * 2], l1 = Ml[i1 * 2 + 1];
    float M = fmaxf(m0, m1);
    float w0 = exp2f(m0 - M), w1 = exp2f(m1 - M);
    float inv = 1.f / fmaxf(w0 * l0 + w1 * l1, 1e-30f);
    f32x4 a = *(const f32x4*)&Op[i0 * 64 + d4 * 4];
    f32x4 b = *(const f32x4*)&Op[i1 * 64 + d4 * 4];
    ushort4 pk;
    pk.x = f2bf((w0 * a[0] + w1 * b[0]) * inv);
    pk.y = f2bf((w0 * a[1] + w1 * b[1]) * inv);
    pk.z = f2bf((w0 * a[2] + w1 * b[2]) * inv);
    pk.w = f2bf((w0 * a[3] + w1 * b[3]) * inv);
    *(ushort4*)&Cat[(size_t)s * D_ + h * 64 + d4 * 4] = pk;
}

extern "C" void kernel_launch(void* const* d_in, const int* in_sizes, int n_in,
                              void* d_out, int out_size, void* d_ws, size_t ws_size,
                              hipStream_t stream) {
    const float* enc_q = (const float*)d_in[0];
    const float* enc_k = (const float*)d_in[1];
    const float* enc_v = (const float*)d_in[2];
    const float* W_q   = (const float*)d_in[3];
    const float* W_k   = (const float*)d_in[4];
    const float* W_v   = (const float*)d_in[5];
    const float* W_out = (const float*)d_in[6];
    float* out = (float*)d_out;

    const size_t M1 = 1024 * 1024;
    unsigned short* Eqb = (unsigned short*)d_ws;   // [S][D] bf16 (dead after proj)
    unsigned short* Ekb = Eqb + 2 * M1;
    unsigned short* Evb = Ekb + 2 * M1;
    unsigned short* Wqt = Evb + 2 * M1;            // [H*DK][D] (dead after proj)
    unsigned short* Wkt = Wqt + M1;
    unsigned short* Wvt = Wkt + M1;
    unsigned short* Wot = Wvt + M1;                // [D][H*DV] (live until out_gemm)
    unsigned short* Qb  = Wot + M1;                // [S][H*DK] (pre-scaled by QK_SCALE)
    unsigned short* Kb  = Qb  + 2 * M1;            // [S][H*DK]
    unsigned short* Vtb = Kb  + 2 * M1;            // [H*DV][S] key-permuted
    unsigned short* Cat = Vtb + 2 * M1;            // [S][H*DV]
    // f32 partials overlap the post-proj dead region [Eqb .. Wvt): 18 MiB
    float* Op = (float*)d_ws;                               // 32*2048*64 f32 = 16 MiB
    float* Ml = (float*)((char*)d_ws + 16u * 1024 * 1024);  // 32*2048*2 f32 = 0.5 MiB

    cvt_f32_bf16<<<dim3(2048, 3), 256, 0, stream>>>(enc_q, enc_k, enc_v, Eqb, Ekb, Evb, 524288);
    dim3 tb(32, 32);
    transpose_qkv<<<dim3(2, 32, 48), tb, 0, stream>>>(W_q, W_k, W_v, Wqt, Wkt, Wvt);
    transpose_wo<<<dim3(32, 32), tb, 0, stream>>>(W_out, Wot);
    proj_kernel<<<dim3(16, 8, 3), 256, 0, stream>>>(Eqb, Ekb, Evb, Wqt, Wkt, Wvt, Qb, Kb, Vtb);
    attn_kernel<<<dim3(16, 16, 2), 256, 0, stream>>>(Qb, Kb, Vtb, Op, Ml);
    combine<<<2048, 256, 0, stream>>>(Op, Ml, Cat);
    out_gemm<<<dim3(16, 8), 256, 0, stream>>>(Cat, Wot, out);
}

// Round 6
// 95.064 us; speedup vs baseline: 1.1505x; 1.1505x over previous
//
#include <hip/hip_runtime.h>
#include <hip/hip_bf16.h>

typedef __attribute__((ext_vector_type(8))) short bf16x8;
typedef __attribute__((ext_vector_type(4))) float f32x4;

#define S_  2048
#define D_  1024
#define H_  16
#define QK_SCALE 0.18033688011f  /* (1/8) * log2(e), folded into W_q */

__device__ __forceinline__ unsigned short f2bf(float x) {
    union { float f; unsigned u; } v; v.f = x;
    unsigned r = v.u + 0x7fffu + ((v.u >> 16) & 1u);
    return (unsigned short)(r >> 16);
}

__device__ __forceinline__ float bf2f(unsigned short s) {
    union { unsigned u; float f; } v; v.u = (unsigned)s << 16; return v.f;
}

__device__ __forceinline__ unsigned short bfbits(float x) {
    union { __hip_bfloat16 h; unsigned short s; } c;
    c.h = __float2bfloat16(x);
    return c.s;
}

__device__ __forceinline__ void gload16(const unsigned short* g, unsigned short* l) {
    __builtin_amdgcn_global_load_lds((const __attribute__((address_space(1))) void*)g,
                                     (__attribute__((address_space(3))) void*)l, 16, 0, 0);
}

__device__ __forceinline__ void drain_vm() {
    asm volatile("s_waitcnt vmcnt(0)" ::: "memory");
}

// ---------------- fused prep: cvt x3 + per-head W transpose + Wo transpose ----------------
// blocks [0,6144): cvt; [6144,9216): transpose_qkv; [9216,10240): transpose_wo
__global__ __launch_bounds__(256) void prep(
    const float* __restrict__ eq, const float* __restrict__ ek, const float* __restrict__ ev,
    const float* __restrict__ wq, const float* __restrict__ wk, const float* __restrict__ wv,
    const float* __restrict__ wo,
    unsigned short* __restrict__ oeq, unsigned short* __restrict__ oek,
    unsigned short* __restrict__ oev, unsigned short* __restrict__ owq,
    unsigned short* __restrict__ owk, unsigned short* __restrict__ owv,
    unsigned short* __restrict__ owo) {
    const int bx = blockIdx.x, tid = threadIdx.x;
    if (bx < 6144) {
        const float* in = bx < 2048 ? eq : bx < 4096 ? ek : ev;
        unsigned short* out = bx < 2048 ? oeq : bx < 4096 ? oek : oev;
        int i = (bx & 2047) * 256 + tid;
        float4 v = ((const float4*)in)[i];
        ushort4 o;
        o.x = f2bf(v.x); o.y = f2bf(v.y); o.z = f2bf(v.z); o.w = f2bf(v.w);
        ((ushort4*)out)[i] = o;
        return;
    }
    __shared__ float t[32][33];
    const int tx = tid & 31, ty = tid >> 5;  // 32 x 8, 4 rows each
    if (bx < 9216) {
        int idx = bx - 6144;
        int zh = idx >> 6, rem = idx & 63;
        int which = zh >> 4, h = zh & 15;
        const float* I = (which == 0 ? wq : which == 1 ? wk : wv) + (long)h * 65536;
        unsigned short* O = (which == 0 ? owq : which == 1 ? owk : owv) + (long)h * 65536;
        float sc = which == 0 ? QK_SCALE : 1.0f;
        int c0 = (rem >> 5) * 32, r0 = (rem & 31) * 32;
        #pragma unroll
        for (int r = 0; r < 4; ++r)
            t[ty + r * 8][tx] = I[(long)(r0 + ty + r * 8) * 64 + c0 + tx];
        __syncthreads();
        #pragma unroll
        for (int r = 0; r < 4; ++r)
            O[(long)(c0 + ty + r * 8) * 1024 + r0 + tx] = f2bf(sc * t[tx][ty + r * 8]);
    } else {
        int idx = bx - 9216;
        int c0 = (idx >> 5) * 32, r0 = (idx & 31) * 32;
        #pragma unroll
        for (int r = 0; r < 4; ++r)
            t[ty + r * 8][tx] = wo[(long)(r0 + ty + r * 8) * 1024 + c0 + tx];
        __syncthreads();
        #pragma unroll
        for (int r = 0; r < 4; ++r)
            owo[(long)(c0 + ty + r * 8) * 1024 + r0 + tx] = f2bf(t[tx][ty + r * 8]);
    }
}

// ---------------- 64x128-tile bf16 MFMA GEMM, double-buffered (3 blocks/CU) ----------------
// MODE 0: bf16 C[gm*ldc+gn]; MODE 1: bf16 KEY-PERMUTED transposed store
template<int MODE>
__device__ __forceinline__ void gemm64x128(unsigned short (*As)[64 * 64],
                                           unsigned short (*Bs)[128 * 64],
                                           const unsigned short* __restrict__ A,
                                           const unsigned short* __restrict__ Bt,
                                           void* __restrict__ C, int m0, int n0, int ldc) {
    const int tid = threadIdx.x, wv = tid >> 6, lane = tid & 63, lg = lane >> 4, lr = lane & 15;
    f32x4 acc[4][2] = {};
    const unsigned short* Ab = A + (size_t)m0 * D_;
    const unsigned short* Bb = Bt + (size_t)n0 * D_;
    auto stage = [&](int b, int kt) {
        #pragma unroll
        for (int it = 0; it < 2; ++it) {
            int c = it * 256 + wv * 64 + lane;
            int row = c >> 3, jj = (c & 7) ^ (row & 7);
            gload16(Ab + (size_t)row * D_ + kt * 64 + jj * 8, &As[b][(it * 256 + wv * 64) * 8]);
        }
        #pragma unroll
        for (int it = 0; it < 4; ++it) {
            int c = it * 256 + wv * 64 + lane;
            int row = c >> 3, jj = (c & 7) ^ (row & 7);
            gload16(Bb + (size_t)row * D_ + kt * 64 + jj * 8, &Bs[b][(it * 256 + wv * 64) * 8]);
        }
    };
    stage(0, 0);
    drain_vm();
    __syncthreads();
    int buf = 0;
    for (int kt = 0; kt < 16; ++kt) {
        if (kt + 1 < 16) stage(buf ^ 1, kt + 1);
        #pragma unroll
        for (int kk = 0; kk < 2; ++kk) {
            bf16x8 af[4], bfr[2];
            #pragma unroll
            for (int mf = 0; mf < 4; ++mf) {
                int r = mf * 16 + lr;
                af[mf] = *(const bf16x8*)&As[buf][(r * 8 + ((kk * 4 + lg) ^ (r & 7))) * 8];
            }
            #pragma unroll
            for (int nf = 0; nf < 2; ++nf) {
                int r = wv * 32 + nf * 16 + lr;
                bfr[nf] = *(const bf16x8*)&Bs[buf][(r * 8 + ((kk * 4 + lg) ^ (r & 7))) * 8];
            }
            #pragma unroll
            for (int mf = 0; mf < 4; ++mf)
                #pragma unroll
                for (int nf = 0; nf < 2; ++nf)
                    acc[mf][nf] = __builtin_amdgcn_mfma_f32_16x16x32_bf16(af[mf], bfr[nf], acc[mf][nf], 0, 0, 0);
        }
        drain_vm();
        __syncthreads();
        buf ^= 1;
    }
    #pragma unroll
    for (int mf = 0; mf < 4; ++mf)
        #pragma unroll
        for (int nf = 0; nf < 2; ++nf) {
            if (MODE == 1) {
                // key-permuted transposed store: key 16b+4lg+j -> pos 8lg+4b+j (b = mf&1)
                int gn = n0 + wv * 32 + nf * 16 + lr;
                int pg = m0 + (mf >> 1) * 32 + lg * 8 + (mf & 1) * 4;
                ushort4 pk;
                pk.x = f2bf(acc[mf][nf][0]); pk.y = f2bf(acc[mf][nf][1]);
                pk.z = f2bf(acc[mf][nf][2]); pk.w = f2bf(acc[mf][nf][3]);
                *(ushort4*)&((unsigned short*)C)[(size_t)gn * ldc + pg] = pk;
            } else {
                #pragma unroll
                for (int j = 0; j < 4; ++j) {
                    int gm = m0 + mf * 16 + lg * 4 + j;
                    int gn = n0 + wv * 32 + nf * 16 + lr;
                    ((unsigned short*)C)[(size_t)gm * ldc + gn] = f2bf(acc[mf][nf][j]);
                }
            }
        }
}

__global__ __launch_bounds__(256, 3) void proj_kernel(
    const unsigned short* __restrict__ Eq, const unsigned short* __restrict__ Ek,
    const unsigned short* __restrict__ Ev, const unsigned short* __restrict__ Wqt,
    const unsigned short* __restrict__ Wkt, const unsigned short* __restrict__ Wvt,
    unsigned short* __restrict__ Qb, unsigned short* __restrict__ Kb,
    unsigned short* __restrict__ Vtb) {
    __shared__ alignas(16) unsigned short As[2][64 * 64];
    __shared__ alignas(16) unsigned short Bs[2][128 * 64];
    int m0 = blockIdx.x * 64, n0 = blockIdx.y * 128;
    if (blockIdx.z == 0)      gemm64x128<0>(As, Bs, Eq, Wqt, Qb, m0, n0, 1024);
    else if (blockIdx.z == 1) gemm64x128<0>(As, Bs, Ek, Wkt, Kb, m0, n0, 1024);
    else                      gemm64x128<1>(As, Bs, Ev, Wvt, Vtb, m0, n0, S_);
}

// ---------------- out projection: 64x64 tiles, f32 out ----------------
__global__ __launch_bounds__(256, 2) void out_gemm(const unsigned short* __restrict__ Cat,
                                                   const unsigned short* __restrict__ Wot,
                                                   float* __restrict__ Out) {
    __shared__ alignas(16) unsigned short As[2][64 * 64];
    __shared__ alignas(16) unsigned short Bs[2][64 * 64];
    const int tid = threadIdx.x, wv = tid >> 6, lane = tid & 63, lg = lane >> 4, lr = lane & 15;
    int m0 = blockIdx.x * 64, n0 = blockIdx.y * 64;
    f32x4 acc[4] = {};
    const unsigned short* Ab = Cat + (size_t)m0 * D_;
    const unsigned short* Bb = Wot + (size_t)n0 * D_;
    auto stage = [&](int b, int kt) {
        #pragma unroll
        for (int it = 0; it < 2; ++it) {
            int c = it * 256 + wv * 64 + lane;
            int row = c >> 3, jj = (c & 7) ^ (row & 7);
            gload16(Ab + (size_t)row * D_ + kt * 64 + jj * 8, &As[b][(it * 256 + wv * 64) * 8]);
        }
        #pragma unroll
        for (int it = 0; it < 2; ++it) {
            int c = it * 256 + wv * 64 + lane;
            int row = c >> 3, jj = (c & 7) ^ (row & 7);
            gload16(Bb + (size_t)row * D_ + kt * 64 + jj * 8, &Bs[b][(it * 256 + wv * 64) * 8]);
        }
    };
    stage(0, 0);
    drain_vm();
    __syncthreads();
    int buf = 0;
    for (int kt = 0; kt < 16; ++kt) {
        if (kt + 1 < 16) stage(buf ^ 1, kt + 1);
        #pragma unroll
        for (int kk = 0; kk < 2; ++kk) {
            int ra = wv * 16 + lr;
            bf16x8 af = *(const bf16x8*)&As[buf][(ra * 8 + ((kk * 4 + lg) ^ (ra & 7))) * 8];
            #pragma unroll
            for (int nf = 0; nf < 4; ++nf) {
                int r = nf * 16 + lr;
                bf16x8 bfr = *(const bf16x8*)&Bs[buf][(r * 8 + ((kk * 4 + lg) ^ (r & 7))) * 8];
                acc[nf] = __builtin_amdgcn_mfma_f32_16x16x32_bf16(af, bfr, acc[nf], 0, 0, 0);
            }
        }
        drain_vm();
        __syncthreads();
        buf ^= 1;
    }
    #pragma unroll
    for (int nf = 0; nf < 4; ++nf)
        #pragma unroll
        for (int j = 0; j < 4; ++j)
            Out[(size_t)(m0 + wv * 16 + lg * 4 + j) * 1024 + n0 + nf * 16 + lr] = acc[nf][j];
}

// ---------------- flash attention: 32 q/wave, split-KV x4, defer-max ----------------
// grid (S/128, H, 4), 256 thr (4 waves). Partials: Opb bf16 [slot][q][dv], Ml f32.
__global__ __launch_bounds__(256, 4) void attn_kernel(
    const unsigned short* __restrict__ Qb, const unsigned short* __restrict__ Kb,
    const unsigned short* __restrict__ Vtb, unsigned short* __restrict__ Opb,
    float* __restrict__ Ml) {
    __shared__ alignas(16) unsigned short Ks[2][64 * 64];
    __shared__ alignas(16) unsigned short Vs[2][64 * 64];

    const int h = blockIdx.y, s0 = blockIdx.x * 128;
    const int tid = threadIdx.x, wv = tid >> 6, lane = tid & 63, lg = lane >> 4, lr = lane & 15;

    const unsigned short* qrA = Qb + (size_t)(s0 + wv * 32 + lr) * D_ + h * 64;
    const unsigned short* qrB = qrA + 16 * D_;
    const bf16x8 qA0 = *(const bf16x8*)(qrA + lg * 8);
    const bf16x8 qA1 = *(const bf16x8*)(qrA + 32 + lg * 8);
    const bf16x8 qB0 = *(const bf16x8*)(qrB + lg * 8);
    const bf16x8 qB1 = *(const bf16x8*)(qrB + 32 + lg * 8);

    float mA = 0.f, mB = 0.f, lA = 0.f, lB = 0.f;
    f32x4 oA[4] = {}, oB[4] = {};

    const unsigned short* KhB = Kb + h * 64;
    const unsigned short* VhB = Vtb + (size_t)(h * 64) * S_;  // key-permuted [64 dv][S]

    auto stage = [&](int b, int t) {
        #pragma unroll
        for (int it = 0; it < 2; ++it) {
            int c = it * 256 + wv * 64 + lane;
            int row = c >> 3, jj = (c & 7) ^ (row & 7);
            gload16(KhB + (size_t)(t * 64 + row) * D_ + jj * 8, &Ks[b][(it * 256 + wv * 64) * 8]);
        }
        #pragma unroll
        for (int it = 0; it < 2; ++it) {
            int c = it * 256 + wv * 64 + lane;
            int row = c >> 3, jj = (c & 7) ^ (row & 7);
            gload16(VhB + (size_t)row * S_ + t * 64 + jj * 8, &Vs[b][(it * 256 + wv * 64) * 8]);
        }
    };

    const int t0 = blockIdx.z * 8;   // 8 KV tiles per split
    stage(0, t0);
    drain_vm();
    __syncthreads();
    int buf = 0;
    for (int tt = 0; tt < 8; ++tt) {
        if (tt + 1 < 8) stage(buf ^ 1, t0 + tt + 1);
        const unsigned short* K_ = Ks[buf];
        const unsigned short* V_ = Vs[buf];

        // scores (pre-scaled via W_q): key = n*16 + lg*4 + j, q = lr
        f32x4 sa[4] = {}, sb[4] = {};
        __builtin_amdgcn_s_setprio(1);
        #pragma unroll
        for (int kk = 0; kk < 2; ++kk) {
            bf16x8 qa = kk ? qA1 : qA0;
            bf16x8 qb = kk ? qB1 : qB0;
            #pragma unroll
            for (int n = 0; n < 4; ++n) {
                int r = n * 16 + lr;
                bf16x8 kf = *(const bf16x8*)&K_[(r * 8 + ((kk * 4 + lg) ^ (r & 7))) * 8];
                sa[n] = __builtin_amdgcn_mfma_f32_16x16x32_bf16(kf, qa, sa[n], 0, 0, 0);
                sb[n] = __builtin_amdgcn_mfma_f32_16x16x32_bf16(kf, qb, sb[n], 0, 0, 0);
            }
        }
        __builtin_amdgcn_s_setprio(0);

        float mxA = sa[0][0], mxB = sb[0][0];
        #pragma unroll
        for (int n = 0; n < 4; ++n)
            #pragma unroll
            for (int j = 0; j < 4; ++j) {
                mxA = fmaxf(mxA, sa[n][j]);
                mxB = fmaxf(mxB, sb[n][j]);
            }
        if (__any((mxA > mA + 11.f) || (mxB > mB + 11.f))) {
            mxA = fmaxf(mxA, __shfl_xor(mxA, 16)); mxA = fmaxf(mxA, __shfl_xor(mxA, 32));
            mxB = fmaxf(mxB, __shfl_xor(mxB, 16)); mxB = fmaxf(mxB, __shfl_xor(mxB, 32));
            float nA = fmaxf(mA, mxA), nB = fmaxf(mB, mxB);
            float aA = exp2f(mA - nA), aB = exp2f(mB - nB);
            mA = nA; mB = nB; lA *= aA; lB *= aB;
            #pragma unroll
            for (int n = 0; n < 4; ++n) { oA[n] *= aA; oB[n] *= aB; }
        }
        float rsA = 0.f, rsB = 0.f;
        #pragma unroll
        for (int n = 0; n < 4; ++n)
            #pragma unroll
            for (int j = 0; j < 4; ++j) {
                float pa = exp2f(sa[n][j] - mA);
                float pb = exp2f(sb[n][j] - mB);
                sa[n][j] = pa; rsA += pa;
                sb[n][j] = pb; rsB += pb;
            }
        lA += rsA; lB += rsB;

        bf16x8 pA[2], pB[2];
        #pragma unroll
        for (int kk = 0; kk < 2; ++kk) {
            union { bf16x8 v; unsigned short s[8]; } ua, ub;
            #pragma unroll
            for (int i = 0; i < 4; ++i) {
                ua.s[i]     = bfbits(sa[2 * kk][i]);
                ua.s[4 + i] = bfbits(sa[2 * kk + 1][i]);
                ub.s[i]     = bfbits(sb[2 * kk][i]);
                ub.s[4 + i] = bfbits(sb[2 * kk + 1][i]);
            }
            pA[kk] = ua.v; pB[kk] = ub.v;
        }
        __builtin_amdgcn_s_setprio(1);
        #pragma unroll
        for (int n = 0; n < 4; ++n) {
            int r = n * 16 + lr;
            #pragma unroll
            for (int kk = 0; kk < 2; ++kk) {
                bf16x8 vf = *(const bf16x8*)&V_[(r * 8 + ((kk * 4 + lg) ^ (r & 7))) * 8];
                oA[n] = __builtin_amdgcn_mfma_f32_16x16x32_bf16(vf, pA[kk], oA[n], 0, 0, 0);
                oB[n] = __builtin_amdgcn_mfma_f32_16x16x32_bf16(vf, pB[kk], oB[n], 0, 0, 0);
            }
        }
        __builtin_amdgcn_s_setprio(0);
        drain_vm();
        __syncthreads();
        buf ^= 1;
    }
    lA += __shfl_xor(lA, 16); lA += __shfl_xor(lA, 32);
    lB += __shfl_xor(lB, 16); lB += __shfl_xor(lB, 32);

    const int slot = blockIdx.z * 16 + h;
    size_t qa = (size_t)s0 + wv * 32 + lr, qb = qa + 16;
    size_t baseA = ((size_t)slot * S_ + qa) * 64;
    size_t baseB = ((size_t)slot * S_ + qb) * 64;
    #pragma unroll
    for (int n = 0; n < 4; ++n) {
        ushort4 ka, kb2;
        ka.x  = f2bf(oA[n][0]); ka.y  = f2bf(oA[n][1]);
        ka.z  = f2bf(oA[n][2]); ka.w  = f2bf(oA[n][3]);
        kb2.x = f2bf(oB[n][0]); kb2.y = f2bf(oB[n][1]);
        kb2.z = f2bf(oB[n][2]); kb2.w = f2bf(oB[n][3]);
        *(ushort4*)&Opb[baseA + n * 16 + lg * 4] = ka;
        *(ushort4*)&Opb[baseB + n * 16 + lg * 4] = kb2;
    }
    if (lg == 0) {
        size_t miA = (size_t)slot * S_ + qa, miB = (size_t)slot * S_ + qb;
        Ml[miA * 2] = mA; Ml[miA * 2 + 1] = lA;
        Ml[miB * 2] = mB; Ml[miB * 2 + 1] = lB;
    }
}

// ---------------- combine the 4 KV-quarters ----------------
__global__ __launch_bounds__(256) void combine(const unsigned short* __restrict__ Opb,
                                               const float* __restrict__ Ml,
                                               unsigned short* __restrict__ Cat) {
    int gid = blockIdx.x * 256 + threadIdx.x;          // 16(d4) * 2048(s) * 16(h)
    int d4 = gid & 15, s = (gid >> 4) & 2047, h = gid >> 15;
    float m[4], l[4];
    #pragma unroll
    for (int i = 0; i < 4; ++i) {
        size_t mi = ((size_t)(i * 16 + h) * S_ + s) * 2;
        m[i] = Ml[mi]; l[i] = Ml[mi + 1];
    }
    float M = fmaxf(fmaxf(m[0], m[1]), fmaxf(m[2], m[3]));
    float w[4], denom = 0.f;
    #pragma unroll
    for (int i = 0; i < 4; ++i) { w[i] = exp2f(m[i] - M); denom += w[i] * l[i]; }
    float inv = 1.f / fmaxf(denom, 1e-30f);
    float o0 = 0.f, o1 = 0.f, o2 = 0.f, o3 = 0.f;
    #pragma unroll
    for (int i = 0; i < 4; ++i) {
        ushort4 u = *(const ushort4*)&Opb[((size_t)(i * 16 + h) * S_ + s) * 64 + d4 * 4];
        o0 += w[i] * bf2f(u.x); o1 += w[i] * bf2f(u.y);
        o2 += w[i] * bf2f(u.z); o3 += w[i] * bf2f(u.w);
    }
    ushort4 pk;
    pk.x = f2bf(o0 * inv); pk.y = f2bf(o1 * inv);
    pk.z = f2bf(o2 * inv); pk.w = f2bf(o3 * inv);
    *(ushort4*)&Cat[(size_t)s * D_ + h * 64 + d4 * 4] = pk;
}

extern "C" void kernel_launch(void* const* d_in, const int* in_sizes, int n_in,
                              void* d_out, int out_size, void* d_ws, size_t ws_size,
                              hipStream_t stream) {
    const float* enc_q = (const float*)d_in[0];
    const float* enc_k = (const float*)d_in[1];
    const float* enc_v = (const float*)d_in[2];
    const float* W_q   = (const float*)d_in[3];
    const float* W_k   = (const float*)d_in[4];
    const float* W_v   = (const float*)d_in[5];
    const float* W_out = (const float*)d_in[6];
    float* out = (float*)d_out;

    const size_t M1 = 1024 * 1024;
    unsigned short* Eqb = (unsigned short*)d_ws;   // [S][D] bf16 (dead after proj)
    unsigned short* Ekb = Eqb + 2 * M1;
    unsigned short* Evb = Ekb + 2 * M1;
    unsigned short* Wqt = Evb + 2 * M1;            // [H*DK][D] (dead after proj)
    unsigned short* Wkt = Wqt + M1;
    unsigned short* Wvt = Wkt + M1;
    unsigned short* Wot = Wvt + M1;                // [D][H*DV] (live until out_gemm)
    unsigned short* Qb  = Wot + M1;                // [S][H*DK] (pre-scaled by QK_SCALE)
    unsigned short* Kb  = Qb  + 2 * M1;            // [S][H*DK]
    unsigned short* Vtb = Kb  + 2 * M1;            // [H*DV][S] key-permuted
    unsigned short* Cat = Vtb + 2 * M1;            // [S][H*DV]
    // partials overlap the post-proj dead region [Eqb .. Wvt) = 18 MiB:
    unsigned short* Opb = (unsigned short*)d_ws;             // 64*2048*64 bf16 = 16.78 MiB
    float* Ml = (float*)((char*)d_ws + 17u * 1024 * 1024);   // 64*2048*2 f32 = 1 MiB

    prep<<<10240, 256, 0, stream>>>(enc_q, enc_k, enc_v, W_q, W_k, W_v, W_out,
                                    Eqb, Ekb, Evb, Wqt, Wkt, Wvt, Wot);
    proj_kernel<<<dim3(32, 8, 3), 256, 0, stream>>>(Eqb, Ekb, Evb, Wqt, Wkt, Wvt, Qb, Kb, Vtb);
    attn_kernel<<<dim3(16, 16, 4), 256, 0, stream>>>(Qb, Kb, Vtb, Opb, Ml);
    combine<<<2048, 256, 0, stream>>>(Opb, Ml, Cat);
    out_gemm<<<dim3(32, 16), 256, 0, stream>>>(Cat, Wot, out);
}

// Round 7
// 93.455 us; speedup vs baseline: 1.1703x; 1.0172x over previous
//
#include <hip/hip_runtime.h>
#include <hip/hip_bf16.h>

typedef __attribute__((ext_vector_type(8))) short bf16x8;
typedef __attribute__((ext_vector_type(4))) float f32x4;

#define S_  2048
#define D_  1024
#define H_  16
#define QK_SCALE 0.18033688011f  /* (1/8) * log2(e), folded into W_q */

__device__ __forceinline__ unsigned short f2bf(float x) {
    union { float f; unsigned u; } v; v.f = x;
    unsigned r = v.u + 0x7fffu + ((v.u >> 16) & 1u);
    return (unsigned short)(r >> 16);
}

__device__ __forceinline__ float bf2f(unsigned short s) {
    union { unsigned u; float f; } v; v.u = (unsigned)s << 16; return v.f;
}

__device__ __forceinline__ unsigned short bfbits(float x) {
    union { __hip_bfloat16 h; unsigned short s; } c;
    c.h = __float2bfloat16(x);
    return c.s;
}

__device__ __forceinline__ float fm3(float a, float b, float c) {
    return fmaxf(fmaxf(a, b), c);   // clang fuses to v_max3_f32
}

__device__ __forceinline__ void gload16(const unsigned short* g, unsigned short* l) {
    __builtin_amdgcn_global_load_lds((const __attribute__((address_space(1))) void*)g,
                                     (__attribute__((address_space(3))) void*)l, 16, 0, 0);
}

__device__ __forceinline__ void drain_vm() {
    asm volatile("s_waitcnt vmcnt(0)" ::: "memory");
}

// ---------------- fused prep: cvt x3 + per-head W transpose + Wo transpose ----------------
// blocks [0,6144): cvt; [6144,9216): transpose_qkv; [9216,10240): transpose_wo
__global__ __launch_bounds__(256) void prep(
    const float* __restrict__ eq, const float* __restrict__ ek, const float* __restrict__ ev,
    const float* __restrict__ wq, const float* __restrict__ wk, const float* __restrict__ wv,
    const float* __restrict__ wo,
    unsigned short* __restrict__ oeq, unsigned short* __restrict__ oek,
    unsigned short* __restrict__ oev, unsigned short* __restrict__ owq,
    unsigned short* __restrict__ owk, unsigned short* __restrict__ owv,
    unsigned short* __restrict__ owo) {
    const int bx = blockIdx.x, tid = threadIdx.x;
    if (bx < 6144) {
        const float* in = bx < 2048 ? eq : bx < 4096 ? ek : ev;
        unsigned short* out = bx < 2048 ? oeq : bx < 4096 ? oek : oev;
        int i = (bx & 2047) * 256 + tid;
        float4 v = ((const float4*)in)[i];
        ushort4 o;
        o.x = f2bf(v.x); o.y = f2bf(v.y); o.z = f2bf(v.z); o.w = f2bf(v.w);
        ((ushort4*)out)[i] = o;
        return;
    }
    __shared__ float t[32][33];
    const int tx = tid & 31, ty = tid >> 5;  // 32 x 8, 4 rows each
    if (bx < 9216) {
        int idx = bx - 6144;
        int zh = idx >> 6, rem = idx & 63;
        int which = zh >> 4, h = zh & 15;
        const float* I = (which == 0 ? wq : which == 1 ? wk : wv) + (long)h * 65536;
        unsigned short* O = (which == 0 ? owq : which == 1 ? owk : owv) + (long)h * 65536;
        float sc = which == 0 ? QK_SCALE : 1.0f;
        int c0 = (rem >> 5) * 32, r0 = (rem & 31) * 32;
        #pragma unroll
        for (int r = 0; r < 4; ++r)
            t[ty + r * 8][tx] = I[(long)(r0 + ty + r * 8) * 64 + c0 + tx];
        __syncthreads();
        #pragma unroll
        for (int r = 0; r < 4; ++r)
            O[(long)(c0 + ty + r * 8) * 1024 + r0 + tx] = f2bf(sc * t[tx][ty + r * 8]);
    } else {
        int idx = bx - 9216;
        int c0 = (idx >> 5) * 32, r0 = (idx & 31) * 32;
        #pragma unroll
        for (int r = 0; r < 4; ++r)
            t[ty + r * 8][tx] = wo[(long)(r0 + ty + r * 8) * 1024 + c0 + tx];
        __syncthreads();
        #pragma unroll
        for (int r = 0; r < 4; ++r)
            owo[(long)(c0 + ty + r * 8) * 1024 + r0 + tx] = f2bf(t[tx][ty + r * 8]);
    }
}

// ---------------- 64x128-tile bf16 MFMA GEMM, double-buffered (3 blocks/CU) ----------------
// MODE 0: bf16 C[gm*ldc+gn]; MODE 1: bf16 KEY-PERMUTED transposed store
template<int MODE>
__device__ __forceinline__ void gemm64x128(unsigned short (*As)[64 * 64],
                                           unsigned short (*Bs)[128 * 64],
                                           const unsigned short* __restrict__ A,
                                           const unsigned short* __restrict__ Bt,
                                           void* __restrict__ C, int m0, int n0, int ldc) {
    const int tid = threadIdx.x, wv = tid >> 6, lane = tid & 63, lg = lane >> 4, lr = lane & 15;
    f32x4 acc[4][2] = {};
    const unsigned short* Ab = A + (size_t)m0 * D_;
    const unsigned short* Bb = Bt + (size_t)n0 * D_;
    auto stage = [&](int b, int kt) {
        #pragma unroll
        for (int it = 0; it < 2; ++it) {
            int c = it * 256 + wv * 64 + lane;
            int row = c >> 3, jj = (c & 7) ^ (row & 7);
            gload16(Ab + (size_t)row * D_ + kt * 64 + jj * 8, &As[b][(it * 256 + wv * 64) * 8]);
        }
        #pragma unroll
        for (int it = 0; it < 4; ++it) {
            int c = it * 256 + wv * 64 + lane;
            int row = c >> 3, jj = (c & 7) ^ (row & 7);
            gload16(Bb + (size_t)row * D_ + kt * 64 + jj * 8, &Bs[b][(it * 256 + wv * 64) * 8]);
        }
    };
    stage(0, 0);
    drain_vm();
    __syncthreads();
    int buf = 0;
    for (int kt = 0; kt < 16; ++kt) {
        if (kt + 1 < 16) stage(buf ^ 1, kt + 1);
        #pragma unroll
        for (int kk = 0; kk < 2; ++kk) {
            bf16x8 af[4], bfr[2];
            #pragma unroll
            for (int mf = 0; mf < 4; ++mf) {
                int r = mf * 16 + lr;
                af[mf] = *(const bf16x8*)&As[buf][(r * 8 + ((kk * 4 + lg) ^ (r & 7))) * 8];
            }
            #pragma unroll
            for (int nf = 0; nf < 2; ++nf) {
                int r = wv * 32 + nf * 16 + lr;
                bfr[nf] = *(const bf16x8*)&Bs[buf][(r * 8 + ((kk * 4 + lg) ^ (r & 7))) * 8];
            }
            #pragma unroll
            for (int mf = 0; mf < 4; ++mf)
                #pragma unroll
                for (int nf = 0; nf < 2; ++nf)
                    acc[mf][nf] = __builtin_amdgcn_mfma_f32_16x16x32_bf16(af[mf], bfr[nf], acc[mf][nf], 0, 0, 0);
        }
        drain_vm();
        __syncthreads();
        buf ^= 1;
    }
    #pragma unroll
    for (int mf = 0; mf < 4; ++mf)
        #pragma unroll
        for (int nf = 0; nf < 2; ++nf) {
            if (MODE == 1) {
                // key-permuted transposed store: key 16b+4lg+j -> pos 8lg+4b+j (b = mf&1)
                int gn = n0 + wv * 32 + nf * 16 + lr;
                int pg = m0 + (mf >> 1) * 32 + lg * 8 + (mf & 1) * 4;
                ushort4 pk;
                pk.x = f2bf(acc[mf][nf][0]); pk.y = f2bf(acc[mf][nf][1]);
                pk.z = f2bf(acc[mf][nf][2]); pk.w = f2bf(acc[mf][nf][3]);
                *(ushort4*)&((unsigned short*)C)[(size_t)gn * ldc + pg] = pk;
            } else {
                #pragma unroll
                for (int j = 0; j < 4; ++j) {
                    int gm = m0 + mf * 16 + lg * 4 + j;
                    int gn = n0 + wv * 32 + nf * 16 + lr;
                    ((unsigned short*)C)[(size_t)gm * ldc + gn] = f2bf(acc[mf][nf][j]);
                }
            }
        }
}

__global__ __launch_bounds__(256, 3) void proj_kernel(
    const unsigned short* __restrict__ Eq, const unsigned short* __restrict__ Ek,
    const unsigned short* __restrict__ Ev, const unsigned short* __restrict__ Wqt,
    const unsigned short* __restrict__ Wkt, const unsigned short* __restrict__ Wvt,
    unsigned short* __restrict__ Qb, unsigned short* __restrict__ Kb,
    unsigned short* __restrict__ Vtb) {
    __shared__ alignas(16) unsigned short As[2][64 * 64];
    __shared__ alignas(16) unsigned short Bs[2][128 * 64];
    int m0 = blockIdx.x * 64, n0 = blockIdx.y * 128;
    if (blockIdx.z == 0)      gemm64x128<0>(As, Bs, Eq, Wqt, Qb, m0, n0, 1024);
    else if (blockIdx.z == 1) gemm64x128<0>(As, Bs, Ek, Wkt, Kb, m0, n0, 1024);
    else                      gemm64x128<1>(As, Bs, Ev, Wvt, Vtb, m0, n0, S_);
}

// ---------------- out projection: 64x64 tiles, f32 out ----------------
__global__ __launch_bounds__(256, 2) void out_gemm(const unsigned short* __restrict__ Cat,
                                                   const unsigned short* __restrict__ Wot,
                                                   float* __restrict__ Out) {
    __shared__ alignas(16) unsigned short As[2][64 * 64];
    __shared__ alignas(16) unsigned short Bs[2][64 * 64];
    const int tid = threadIdx.x, wv = tid >> 6, lane = tid & 63, lg = lane >> 4, lr = lane & 15;
    int m0 = blockIdx.x * 64, n0 = blockIdx.y * 64;
    f32x4 acc[4] = {};
    const unsigned short* Ab = Cat + (size_t)m0 * D_;
    const unsigned short* Bb = Wot + (size_t)n0 * D_;
    auto stage = [&](int b, int kt) {
        #pragma unroll
        for (int it = 0; it < 2; ++it) {
            int c = it * 256 + wv * 64 + lane;
            int row = c >> 3, jj = (c & 7) ^ (row & 7);
            gload16(Ab + (size_t)row * D_ + kt * 64 + jj * 8, &As[b][(it * 256 + wv * 64) * 8]);
        }
        #pragma unroll
        for (int it = 0; it < 2; ++it) {
            int c = it * 256 + wv * 64 + lane;
            int row = c >> 3, jj = (c & 7) ^ (row & 7);
            gload16(Bb + (size_t)row * D_ + kt * 64 + jj * 8, &Bs[b][(it * 256 + wv * 64) * 8]);
        }
    };
    stage(0, 0);
    drain_vm();
    __syncthreads();
    int buf = 0;
    for (int kt = 0; kt < 16; ++kt) {
        if (kt + 1 < 16) stage(buf ^ 1, kt + 1);
        #pragma unroll
        for (int kk = 0; kk < 2; ++kk) {
            int ra = wv * 16 + lr;
            bf16x8 af = *(const bf16x8*)&As[buf][(ra * 8 + ((kk * 4 + lg) ^ (ra & 7))) * 8];
            #pragma unroll
            for (int nf = 0; nf < 4; ++nf) {
                int r = nf * 16 + lr;
                bf16x8 bfr = *(const bf16x8*)&Bs[buf][(r * 8 + ((kk * 4 + lg) ^ (r & 7))) * 8];
                acc[nf] = __builtin_amdgcn_mfma_f32_16x16x32_bf16(af, bfr, acc[nf], 0, 0, 0);
            }
        }
        drain_vm();
        __syncthreads();
        buf ^= 1;
    }
    #pragma unroll
    for (int nf = 0; nf < 4; ++nf)
        #pragma unroll
        for (int j = 0; j < 4; ++j)
            Out[(size_t)(m0 + wv * 16 + lg * 4 + j) * 1024 + n0 + nf * 16 + lr] = acc[nf][j];
}

// ---------------- flash attention: 2-deep pipelined, split-KV x4 ----------------
// grid (S/128, H, 4), 256 thr (4 waves); wave owns 32 q rows as two 16-row sets.
// Pipeline: per tile t: sync -> stage(t+2) -> QK(t+1) -> softmax(t) [overlaps QK's
// MFMA] -> pack -> PV(t). K dbuf, V tribuf (slot (t)%3 live until PV(t)).
__global__ __launch_bounds__(256, 3) void attn_kernel(
    const unsigned short* __restrict__ Qb, const unsigned short* __restrict__ Kb,
    const unsigned short* __restrict__ Vtb, unsigned short* __restrict__ Opb,
    float* __restrict__ Ml) {
    __shared__ alignas(16) unsigned short Ks[2][64 * 64];
    __shared__ alignas(16) unsigned short Vs[3][64 * 64];

    const int h = blockIdx.y, s0 = blockIdx.x * 128;
    const int tid = threadIdx.x, wv = tid >> 6, lane = tid & 63, lg = lane >> 4, lr = lane & 15;

    const unsigned short* qrA = Qb + (size_t)(s0 + wv * 32 + lr) * D_ + h * 64;
    const unsigned short* qrB = qrA + 16 * D_;
    const bf16x8 qA0 = *(const bf16x8*)(qrA + lg * 8);
    const bf16x8 qA1 = *(const bf16x8*)(qrA + 32 + lg * 8);
    const bf16x8 qB0 = *(const bf16x8*)(qrB + lg * 8);
    const bf16x8 qB1 = *(const bf16x8*)(qrB + 32 + lg * 8);

    float mA = 0.f, mB = 0.f, lA = 0.f, lB = 0.f;
    f32x4 oA[4] = {}, oB[4] = {};
    f32x4 sa[2][4], sb[2][4];   // 2-deep score state, indexed by tt&1 (unrolled)

    const unsigned short* KhB = Kb + h * 64;
    const unsigned short* VhB = Vtb + (size_t)(h * 64) * S_;  // key-permuted [64 dv][S]
    const int t0 = blockIdx.z * 8;

    auto stageL = [&](int u) {   // tile t0+u -> Ks[u&1], Vs[u%3]
        int t = t0 + u;
        #pragma unroll
        for (int it = 0; it < 2; ++it) {
            int c = it * 256 + wv * 64 + lane;
            int row = c >> 3, jj = (c & 7) ^ (row & 7);
            gload16(KhB + (size_t)(t * 64 + row) * D_ + jj * 8, &Ks[u & 1][(it * 256 + wv * 64) * 8]);
        }
        #pragma unroll
        for (int it = 0; it < 2; ++it) {
            int c = it * 256 + wv * 64 + lane;
            int row = c >> 3, jj = (c & 7) ^ (row & 7);
            gload16(VhB + (size_t)row * S_ + t * 64 + jj * 8, &Vs[u % 3][(it * 256 + wv * 64) * 8]);
        }
    };
    auto qk = [&](int u) {       // scores for tile t0+u from Ks[u&1] -> sa/sb[u&1]
        const unsigned short* K_ = Ks[u & 1];
        __builtin_amdgcn_s_setprio(1);
        #pragma unroll
        for (int kk = 0; kk < 2; ++kk) {
            bf16x8 qa = kk ? qA1 : qA0;
            bf16x8 qb = kk ? qB1 : qB0;
            #pragma unroll
            for (int n = 0; n < 4; ++n) {
                int r = n * 16 + lr;
                bf16x8 kf = *(const bf16x8*)&K_[(r * 8 + ((kk * 4 + lg) ^ (r & 7))) * 8];
                if (kk == 0) {
                    f32x4 z = {};
                    sa[u & 1][n] = __builtin_amdgcn_mfma_f32_16x16x32_bf16(kf, qa, z, 0, 0, 0);
                    sb[u & 1][n] = __builtin_amdgcn_mfma_f32_16x16x32_bf16(kf, qb, z, 0, 0, 0);
                } else {
                    sa[u & 1][n] = __builtin_amdgcn_mfma_f32_16x16x32_bf16(kf, qa, sa[u & 1][n], 0, 0, 0);
                    sb[u & 1][n] = __builtin_amdgcn_mfma_f32_16x16x32_bf16(kf, qb, sb[u & 1][n], 0, 0, 0);
                }
            }
        }
        __builtin_amdgcn_s_setprio(0);
    };

    stageL(0);
    stageL(1);
    #pragma unroll
    for (int tt = 0; tt < 8; ++tt) {
        __syncthreads();   // implicit vmcnt(0): tiles <= tt+1 staged and visible
        if (tt == 0) {
            qk(0);         // must read Ks[0] before stage(2) can overwrite it
            stageL(2);
        } else if (tt + 2 < 8) {
            stageL(tt + 2);
        }
        if (tt + 1 < 8) qk(tt + 1);   // independent of softmax(tt) below

        f32x4* sA = sa[tt & 1];
        f32x4* sB = sb[tt & 1];
        // per-lane max via v_max3 trees
        float mxA, mxB;
        {
            float a0 = fm3(sA[0][0], sA[0][1], sA[0][2]);
            float a1 = fm3(sA[0][3], sA[1][0], sA[1][1]);
            float a2 = fm3(sA[1][2], sA[1][3], sA[2][0]);
            float a3 = fm3(sA[2][1], sA[2][2], sA[2][3]);
            float a4 = fm3(sA[3][0], sA[3][1], sA[3][2]);
            mxA = fm3(fm3(a0, a1, a2), fmaxf(a3, a4), sA[3][3]);
            float b0 = fm3(sB[0][0], sB[0][1], sB[0][2]);
            float b1 = fm3(sB[0][3], sB[1][0], sB[1][1]);
            float b2 = fm3(sB[1][2], sB[1][3], sB[2][0]);
            float b3 = fm3(sB[2][1], sB[2][2], sB[2][3]);
            float b4 = fm3(sB[3][0], sB[3][1], sB[3][2]);
            mxB = fm3(fm3(b0, b1, b2), fmaxf(b3, b4), sB[3][3]);
        }
        if (__any((mxA > mA + 11.f) || (mxB > mB + 11.f))) {
            mxA = fmaxf(mxA, __shfl_xor(mxA, 16)); mxA = fmaxf(mxA, __shfl_xor(mxA, 32));
            mxB = fmaxf(mxB, __shfl_xor(mxB, 16)); mxB = fmaxf(mxB, __shfl_xor(mxB, 32));
            float nA = fmaxf(mA, mxA), nB = fmaxf(mB, mxB);
            float aA = exp2f(mA - nA), aB = exp2f(mB - nB);
            mA = nA; mB = nB; lA *= aA; lB *= aB;
            #pragma unroll
            for (int n = 0; n < 4; ++n) { oA[n] *= aA; oB[n] *= aB; }
        }
        float rsA = 0.f, rsB = 0.f;
        #pragma unroll
        for (int n = 0; n < 4; ++n)
            #pragma unroll
            for (int j = 0; j < 4; ++j) {
                float pa = exp2f(sA[n][j] - mA);
                float pb = exp2f(sB[n][j] - mB);
                sA[n][j] = pa; rsA += pa;
                sB[n][j] = pb; rsB += pb;
            }
        lA += rsA; lB += rsB;

        bf16x8 pA[2], pB[2];
        #pragma unroll
        for (int kk = 0; kk < 2; ++kk) {
            union { bf16x8 v; unsigned short s[8]; } ua, ub;
            #pragma unroll
            for (int i = 0; i < 4; ++i) {
                ua.s[i]     = bfbits(sA[2 * kk][i]);
                ua.s[4 + i] = bfbits(sA[2 * kk + 1][i]);
                ub.s[i]     = bfbits(sB[2 * kk][i]);
                ub.s[4 + i] = bfbits(sB[2 * kk + 1][i]);
            }
            pA[kk] = ua.v; pB[kk] = ub.v;
        }
        const unsigned short* V_ = Vs[tt % 3];
        __builtin_amdgcn_s_setprio(1);
        #pragma unroll
        for (int n = 0; n < 4; ++n) {
            int r = n * 16 + lr;
            #pragma unroll
            for (int kk = 0; kk < 2; ++kk) {
                bf16x8 vf = *(const bf16x8*)&V_[(r * 8 + ((kk * 4 + lg) ^ (r & 7))) * 8];
                oA[n] = __builtin_amdgcn_mfma_f32_16x16x32_bf16(vf, pA[kk], oA[n], 0, 0, 0);
                oB[n] = __builtin_amdgcn_mfma_f32_16x16x32_bf16(vf, pB[kk], oB[n], 0, 0, 0);
            }
        }
        __builtin_amdgcn_s_setprio(0);
    }
    lA += __shfl_xor(lA, 16); lA += __shfl_xor(lA, 32);
    lB += __shfl_xor(lB, 16); lB += __shfl_xor(lB, 32);

    const int slot = blockIdx.z * 16 + h;
    size_t qa = (size_t)s0 + wv * 32 + lr, qb = qa + 16;
    size_t baseA = ((size_t)slot * S_ + qa) * 64;
    size_t baseB = ((size_t)slot * S_ + qb) * 64;
    #pragma unroll
    for (int n = 0; n < 4; ++n) {
        ushort4 ka, kb2;
        ka.x  = f2bf(oA[n][0]); ka.y  = f2bf(oA[n][1]);
        ka.z  = f2bf(oA[n][2]); ka.w  = f2bf(oA[n][3]);
        kb2.x = f2bf(oB[n][0]); kb2.y = f2bf(oB[n][1]);
        kb2.z = f2bf(oB[n][2]); kb2.w = f2bf(oB[n][3]);
        *(ushort4*)&Opb[baseA + n * 16 + lg * 4] = ka;
        *(ushort4*)&Opb[baseB + n * 16 + lg * 4] = kb2;
    }
    if (lg == 0) {
        size_t miA = (size_t)slot * S_ + qa, miB = (size_t)slot * S_ + qb;
        Ml[miA * 2] = mA; Ml[miA * 2 + 1] = lA;
        Ml[miB * 2] = mB; Ml[miB * 2 + 1] = lB;
    }
}

// ---------------- combine the 4 KV-quarters ----------------
__global__ __launch_bounds__(256) void combine(const unsigned short* __restrict__ Opb,
                                               const float* __restrict__ Ml,
                                               unsigned short* __restrict__ Cat) {
    int gid = blockIdx.x * 256 + threadIdx.x;          // 16(d4) * 2048(s) * 16(h)
    int d4 = gid & 15, s = (gid >> 4) & 2047, h = gid >> 15;
    float m[4], l[4];
    #pragma unroll
    for (int i = 0; i < 4; ++i) {
        size_t mi = ((size_t)(i * 16 + h) * S_ + s) * 2;
        m[i] = Ml[mi]; l[i] = Ml[mi + 1];
    }
    float M = fmaxf(fmaxf(m[0], m[1]), fmaxf(m[2], m[3]));
    float w[4], denom = 0.f;
    #pragma unroll
    for (int i = 0; i < 4; ++i) { w[i] = exp2f(m[i] - M); denom += w[i] * l[i]; }
    float inv = 1.f / fmaxf(denom, 1e-30f);
    float o0 = 0.f, o1 = 0.f, o2 = 0.f, o3 = 0.f;
    #pragma unroll
    for (int i = 0; i < 4; ++i) {
        ushort4 u = *(const ushort4*)&Opb[((size_t)(i * 16 + h) * S_ + s) * 64 + d4 * 4];
        o0 += w[i] * bf2f(u.x); o1 += w[i] * bf2f(u.y);
        o2 += w[i] * bf2f(u.z); o3 += w[i] * bf2f(u.w);
    }
    ushort4 pk;
    pk.x = f2bf(o0 * inv); pk.y = f2bf(o1 * inv);
    pk.z = f2bf(o2 * inv); pk.w = f2bf(o3 * inv);
    *(ushort4*)&Cat[(size_t)s * D_ + h * 64 + d4 * 4] = pk;
}

extern "C" void kernel_launch(void* const* d_in, const int* in_sizes, int n_in,
                              void* d_out, int out_size, void* d_ws, size_t ws_size,
                              hipStream_t stream) {
    const float* enc_q = (const float*)d_in[0];
    const float* enc_k = (const float*)d_in[1];
    const float* enc_v = (const float*)d_in[2];
    const float* W_q   = (const float*)d_in[3];
    const float* W_k   = (const float*)d_in[4];
    const float* W_v   = (const float*)d_in[5];
    const float* W_out = (const float*)d_in[6];
    float* out = (float*)d_out;

    const size_t M1 = 1024 * 1024;
    unsigned short* Eqb = (unsigned short*)d_ws;   // [S][D] bf16 (dead after proj)
    unsigned short* Ekb = Eqb + 2 * M1;
    unsigned short* Evb = Ekb + 2 * M1;
    unsigned short* Wqt = Evb + 2 * M1;            // [H*DK][D] (dead after proj)
    unsigned short* Wkt = Wqt + M1;
    unsigned short* Wvt = Wkt + M1;
    unsigned short* Wot = Wvt + M1;                // [D][H*DV] (live until out_gemm)
    unsigned short* Qb  = Wot + M1;                // [S][H*DK] (pre-scaled by QK_SCALE)
    unsigned short* Kb  = Qb  + 2 * M1;            // [S][H*DK]
    unsigned short* Vtb = Kb  + 2 * M1;            // [H*DV][S] key-permuted
    unsigned short* Cat = Vtb + 2 * M1;            // [S][H*DV]
    // partials overlap the post-proj dead region [Eqb .. Wvt) = 18 MiB:
    unsigned short* Opb = (unsigned short*)d_ws;             // 64*2048*64 bf16 = 16.78 MiB
    float* Ml = (float*)((char*)d_ws + 17u * 1024 * 1024);   // 64*2048*2 f32 = 1 MiB

    prep<<<10240, 256, 0, stream>>>(enc_q, enc_k, enc_v, W_q, W_k, W_v, W_out,
                                    Eqb, Ekb, Evb, Wqt, Wkt, Wvt, Wot);
    proj_kernel<<<dim3(32, 8, 3), 256, 0, stream>>>(Eqb, Ekb, Evb, Wqt, Wkt, Wvt, Qb, Kb, Vtb);
    attn_kernel<<<dim3(16, 16, 4), 256, 0, stream>>>(Qb, Kb, Vtb, Opb, Ml);
    combine<<<2048, 256, 0, stream>>>(Opb, Ml, Cat);
    out_gemm<<<dim3(32, 16), 256, 0, stream>>>(Cat, Wot, out);
}